// Round 1
// baseline (734.779 us; speedup 1.0000x reference)
//
#include <hip/hip_runtime.h>

#define NEGV -1e30f
static constexpr int BATCH = 64;
static constexpr int NN = 512;
static constexpr int MM = 512;
static constexpr int NM = NN * MM;
static constexpr size_t TOTAL = (size_t)BATCH * NM;
static constexpr int NWAVE = 4;           // waves per DP problem (1 per SIMD)
static constexpr int RPW = NN / NWAVE;    // 128 rows per wave, 2 rows per lane

// lane n <- lane n-1 (whole-wave shift right by 1), 1 VALU op, no LDS.
__device__ __forceinline__ float wave_shr1(float x) {
    int y = __builtin_amdgcn_mov_dpp(__float_as_int(x), 0x138, 0xf, 0xf, true);
    return __int_as_float(y);
}

// raw barrier: lgkmcnt(0) makes the LDS boundary write visible, but vmcnt is
// NOT drained (unlike __syncthreads) -> global prefetch/stores stay in flight.
__device__ __forceinline__ void stepbar() {
    asm volatile("s_waitcnt lgkmcnt(0)" ::: "memory");
    __builtin_amdgcn_s_barrier();
    asm volatile("" ::: "memory");
}

// compile-time float4 component select (folds after macro expansion)
#define F4C(v, c) ((c) == 0 ? (v).x : (c) == 1 ? (v).y : (c) == 2 ? (v).z : (v).w)
// token-paste indirection so macro params expand first
#define XC(a, b) a##b
#define C2(a, b) XC(a, b)
#define QQ(r, s) q##r##_##s
#define Q(r, s) QQ(r, s)

// ---------------------------------------------------------------------------
// K1: 4-wave wavefront DP. Wave w owns rows [128w, 128w+128); lane t owns
// rows i0=128w+2t and i0+1. Cross-lane dep via DPP; cross-wave dep via a
// double-buffered LDS slot + one raw s_barrier per diagonal. All per-row DP
// state in 4 rotating named registers (np(k-1..k-3) + new) -> zero shift movs.
// Since i0 is not 0 mod 4, float4 load/store phase depends on lane parity:
// loads/stores are parity-predicated (1 load + 1 store per wave per step) and
// the D-component select costs one cndmask per cell.
// Branchless interior: out-of-range cells compute harmless ~NEGV/NaN garbage
// that only ever feeds other out-of-range cells; stores guarded, loads clamped.
// ---------------------------------------------------------------------------
template <int DIR>
__device__ __forceinline__ void dp_run(const float* __restrict__ Db,
                                       float* __restrict__ Rp,
                                       const int w, const int lane,
                                       float2* __restrict__ bnd) {
    const int i0 = w * RPW + lane * 2;
    const bool l0 = (lane == 0);
    const bool w0 = (w == 0);
    const int odd = lane & 1;
    const float dgb0 = (w0 && l0) ? 0.f : NEGV;  // diag boundary for cell (0,0)

#define PTRS(r) \
    const float* ldp_##r = DIR ? (Db + (size_t)(NM - 1) - (size_t)(i0 + r) * MM) \
                               : (Db + (size_t)(i0 + r) * MM); \
    float* stp_##r = DIR ? (Rp + (size_t)(NM - 1) - (size_t)(i0 + r) * MM) \
                         : (Rp + (size_t)(i0 + r) * MM);
    PTRS(0) PTRS(1)
#undef PTRS

// load float4 covering logical cols [jc, jc+3] of row r (clamped)
#define LOADG(r, dst, jgexpr) do { \
        int jc_ = (jgexpr); \
        jc_ = jc_ < 0 ? 0 : jc_; jc_ = jc_ > (MM - 4) ? (MM - 4) : jc_; \
        if (DIR) { const float4 t_ = *(const float4*)(C2(ldp_, r) - jc_ - 3); \
                   dst = make_float4(t_.w, t_.z, t_.y, t_.x); } \
        else     { dst = *(const float4*)(C2(ldp_, r) + jc_); } \
    } while (0)

    // rotating np history: slot s holds np(k') with k' = ... (static roles per KK)
    float q0_0 = NEGV, q0_1 = NEGV, q0_2 = NEGV, q0_3 = NEGV;
    float q1_0 = NEGV, q1_1 = NEGV, q1_2 = NEGV, q1_3 = NEGV;
    float4 dc_0, dn_0, dc_1, dn_1;
    LOADG(0, dn_0, 0); dc_0 = dn_0;
    LOADG(1, dn_1, 0); dc_1 = dn_1;

// one DP cell: inputs dg/up/lf, D component (dcomp + parity offset), out dstq
#define CELLBODY(dgv, upv, lfv, dcomp, dreg, dstq) do { \
        const float m_ = fmaxf(fmaxf(dgv, upv), lfv); \
        const float mn_ = fminf(fminf(dgv, upv), lfv); \
        const float md_ = __builtin_amdgcn_fmed3f(dgv, upv, lfv); \
        const float s_ = 1.f + __expf(mn_ - m_) + __expf(md_ - m_); \
        const float d_ = odd ? F4C(dreg, ((dcomp) + 2) & 3) : F4C(dreg, (dcomp) & 3); \
        dstq = d_ + m_ + __logf(s_); \
    } while (0)

// one diagonal. Slots: S0=new np(k), S1=np(k-1), S2=np(k-2), S3=np(k-3).
// LC/LR: lane-parity class + row that rotates+prefetches this step.
// SC/SR: class + row that stores its completed 4-col group this step.
#define STEP(KK, S0, S1, S2, S3, LC, LR, SC, SR) do { \
        const int jj = kbj + (KK); \
        if (odd == (LC)) { C2(dc_, LR) = C2(dn_, LR); \
                           LOADG(LR, C2(dn_, LR), jj - (LR) + 4); } \
        float2 bv; \
        if (!w0) bv = bnd[(((KK) + 1) & 1) * NWAVE + (w - 1)]; \
        else     bv = make_float2(NEGV, NEGV); \
        const float upd = wave_shr1(Q(1, S1)); \
        const float dgd = wave_shr1(Q(1, S2)); \
        const float up0 = l0 ? bv.x : upd; \
        const float dg0 = l0 ? bv.y : dgd; \
        { /* cell: row i0+1 (in-lane deps only) */ \
            const bool jz = (jj == 1); \
            const float lf = jz ? NEGV : Q(1, S1); \
            const float dg = jz ? NEGV : Q(0, S2); \
            const float up = Q(0, S1); \
            CELLBODY(dg, up, lf, (KK) + 3, dc_1, Q(1, S0)); \
        } \
        { /* cell: row i0 (cross-lane / cross-wave deps) */ \
            const bool jz = (jj == 0); \
            const float lf = jz ? NEGV : Q(0, S1); \
            const float dg = jz ? dgb0 : dg0; \
            CELLBODY(dg, up0, lf, (KK), dc_0, Q(0, S0)); \
        } \
        if (odd == (SC)) { \
            const int j_ = jj - (SR); \
            if (j_ >= 3 && j_ < MM) { \
                if (DIR) *(float4*)(C2(stp_, SR) - j_) = \
                    make_float4(Q(SR, S0), Q(SR, S1), Q(SR, S2), Q(SR, S3)); \
                else     *(float4*)(C2(stp_, SR) + j_ - 3) = \
                    make_float4(Q(SR, S3), Q(SR, S2), Q(SR, S1), Q(SR, S0)); \
            } \
        } \
        if (lane == 63) bnd[((KK) & 1) * NWAVE + w] = make_float2(Q(1, S0), Q(1, S1)); \
        stepbar(); \
    } while (0)

    int kbj = -i0;
    for (int kb = 0; kb < NN + MM; kb += 4) {
        STEP(0, 0, 3, 2, 1, 0, 0, 0, 1);
        STEP(1, 1, 0, 3, 2, 0, 1, 1, 0);
        STEP(2, 2, 1, 0, 3, 1, 0, 1, 1);
        STEP(3, 3, 2, 1, 0, 1, 1, 0, 0);
        kbj += 4;
    }

#undef STEP
#undef CELLBODY
#undef LOADG
}

__global__ __launch_bounds__(256, 1) void dp_kernel(const float* __restrict__ D,
                                                    float* __restrict__ Rf,
                                                    float* __restrict__ Rb) {
    __shared__ float2 bnd[2 * NWAVE];  // [parity][wave] boundary (np(k), np(k-1))
    const int blk = blockIdx.x;
    const int b = blk & (BATCH - 1);
    const int dir = blk >> 6;          // block-uniform -> barriers stay converged
    const int tid = (int)threadIdx.x;
    const int w = tid >> 6;
    const int lane = tid & 63;
    const float* __restrict__ Db = D + (size_t)b * NM;
    if (dir) {
        dp_run<1>(Db, Rb + (size_t)b * NM, w, lane, bnd);
    } else {
        dp_run<0>(Db, Rf + (size_t)b * NM, w, lane, bnd);
    }
}

// ---------------------------------------------------------------------------
// block-level max reduction (256 threads)
// ---------------------------------------------------------------------------
__device__ inline float blockMax256(float v) {
    __shared__ float sm[256];
    sm[threadIdx.x] = v;
    __syncthreads();
    for (int s = 128; s > 0; s >>= 1) {
        if ((int)threadIdx.x < s)
            sm[threadIdx.x] = fmaxf(sm[threadIdx.x], sm[threadIdx.x + s]);
        __syncthreads();
    }
    return sm[0];
}

// K2: logit = f + b - d (in place into out, which holds f), per-block max
__global__ __launch_bounds__(256) void logit_kernel(const float4* __restrict__ D,
                                                    const float4* __restrict__ Rb,
                                                    float4* __restrict__ out,
                                                    float* __restrict__ partial) {
    const size_t n4 = TOTAL / 4;
    float mx = NEGV;
    const size_t stride = (size_t)gridDim.x * blockDim.x;
    for (size_t idx = (size_t)blockIdx.x * blockDim.x + threadIdx.x; idx < n4;
         idx += stride) {
        float4 f = out[idx], bb = Rb[idx], d = D[idx];
        float4 v = make_float4(f.x + bb.x - d.x, f.y + bb.y - d.y,
                               f.z + bb.z - d.z, f.w + bb.w - d.w);
        out[idx] = v;
        mx = fmaxf(mx, fmaxf(fmaxf(v.x, v.y), fmaxf(v.z, v.w)));
    }
    float bm = blockMax256(mx);
    if (threadIdx.x == 0) partial[blockIdx.x] = bm;
}

// K3: reduce partials to one scalar
__global__ __launch_bounds__(256) void finalmax_kernel(const float* __restrict__ partial,
                                                       int n,
                                                       float* __restrict__ outmax) {
    float mx = NEGV;
    for (int i = threadIdx.x; i < n; i += 256) mx = fmaxf(mx, partial[i]);
    float bm = blockMax256(mx);
    if (threadIdx.x == 0) *outmax = bm;
}

// K4: out -= max  (GAMMA = T = 1)
__global__ __launch_bounds__(256) void sub_kernel(float4* __restrict__ out,
                                                  const float* __restrict__ maxp) {
    const float mx = *maxp;
    const size_t n4 = TOTAL / 4;
    const size_t stride = (size_t)gridDim.x * blockDim.x;
    for (size_t idx = (size_t)blockIdx.x * blockDim.x + threadIdx.x; idx < n4;
         idx += stride) {
        float4 v = out[idx];
        v.x -= mx; v.y -= mx; v.z -= mx; v.w -= mx;
        out[idx] = v;
    }
}

extern "C" void kernel_launch(void* const* d_in, const int* in_sizes, int n_in,
                              void* d_out, int out_size, void* d_ws, size_t ws_size,
                              hipStream_t stream) {
    const float* D = (const float*)d_in[0];
    float* out = (float*)d_out;      // holds Rf after K1, logit after K2
    float* Rb = (float*)d_ws;        // 64 MB backward DP result
    float* partial = Rb + TOTAL;     // 2048 floats
    float* maxp = partial + 2048;    // 1 float

    dp_kernel<<<128, 256, 0, stream>>>(D, out, Rb);
    logit_kernel<<<2048, 256, 0, stream>>>((const float4*)D, (const float4*)Rb,
                                           (float4*)out, partial);
    finalmax_kernel<<<1, 256, 0, stream>>>(partial, 2048, maxp);
    sub_kernel<<<2048, 256, 0, stream>>>((float4*)out, maxp);
}